// Round 15
// baseline (80.894 us; speedup 1.0000x reference)
//
#include <hip/hip_runtime.h>

constexpr int N_NODES = 100000;
constexpr int N_FEAT  = 512;
constexpr int N_EDGES = 1600000;

// fixed-point packing for LDS u64 accumulation
constexpr float FXS = 1048576.0f;  // 2^20
constexpr float FXB = 32.0f;       // positivity bias; FXB*FXS = 2^25 exact

// binning (R8: narrow; R9: no dynamic sched; R6/R11: no inter-block barriers;
// R13: XCD-sharded bins; R14: W in LDS; R15: 2-deep register dbuf on x loads)
constexpr int BSH    = 8;
constexpr int BINW   = 1 << BSH;                     // 256 nodes/bin
constexpr int NBINS  = (N_NODES + BINW - 1) >> BSH;  // 391
constexpr int NSH    = 8;                            // shards (≈ XCDs)
constexpr int BCAP_S = 768;   // per-(bin,shard): mean 516, +11 sigma
constexpr int NBB    = 500;   // binning blocks
constexpr int CHUNK  = N_EDGES / NBB;                // 3200 (exact)
constexpr int GRID   = 2048;
constexpr int NRB    = GRID - NBB;                   // 1548 rowdot blocks
constexpr int NCUR   = NBINS * NSH;                  // 3128 cursors

typedef float vfloat4 __attribute__((ext_vector_type(4)));

// ws float offsets
constexpr int WS_W    = 0;                    // [0,1024) two cols of w1@w2
constexpr int WS_C    = 1024;                 // c (pad to 1056)
constexpr int WS_CUR  = 1056;                 // NCUR cursors (pad 3200)
constexpr int WS_DEG  = WS_CUR + 3200;        // deg[N] int
constexpr int WS_DINV = WS_DEG + N_NODES;     // dinv[N]
constexpr int WS_G    = WS_DINV + N_NODES;    // g[N,2] (byte%8==0)
constexpr int WS_FXP  = WS_G + 2 * N_NODES;   // u64[N] packed addends
constexpr int WS_BINS = WS_FXP + 2 * N_NODES; // u32[NCUR*BCAP_S] ~9.6MB

static_assert((WS_G * 4) % 8 == 0, "g alignment");
static_assert((WS_FXP * 4) % 8 == 0, "fxp alignment");
static_assert(N_NODES % 4 == 0, "");

// ---- kernel 1: W = w1@w2, c = b1@w2+b2, zero cursors ----
__global__ void k_prep(const float* __restrict__ w1, const float* __restrict__ w2,
                       const float* __restrict__ b1, const float* __restrict__ b2,
                       float* __restrict__ ws) {
    int i = blockIdx.x * blockDim.x + threadIdx.x;
    if (i < NCUR) reinterpret_cast<int*>(ws + WS_CUR)[i] = 0;
    if (i < N_FEAT) {
        float a0 = 0.f, a1 = 0.f;
        for (int m = 0; m < 128; ++m) {
            float w = w1[i * 128 + m];
            a0 += w * w2[m * 2 + 0];
            a1 += w * w2[m * 2 + 1];
        }
        ws[WS_W + i] = a0;
        ws[WS_W + 512 + i] = a1;
        if (i < 2) {
            float s = b2[i];
            for (int m = 0; m < 128; ++m) s += b1[m] * w2[m * 2 + i];
            ws[WS_C + i] = s;
        }
    }
}

__device__ __forceinline__ void rd_load(vfloat4 (&xv)[8], const float* __restrict__ x,
                                        int q, int i4, int j) {
    const vfloat4* xr = reinterpret_cast<const vfloat4*>(x + (size_t)(q * 4 + i4) * N_FEAT);
    #pragma unroll
    for (int k = 0; k < 8; ++k) xv[k] = xr[k * 16 + j];
}

__device__ __forceinline__ void rd_compute(const vfloat4 (&xv)[8],
                                           const vfloat4* __restrict__ W0l,
                                           const vfloat4* __restrict__ W1l,
                                           float2* __restrict__ g, int q, int i4, int j) {
    float a0 = 0.f, a1 = 0.f;
    #pragma unroll
    for (int k = 0; k < 8; ++k) {
        vfloat4 w0 = W0l[k * 16 + j];
        vfloat4 w1 = W1l[k * 16 + j];
        a0 += xv[k].x*w0.x + xv[k].y*w0.y + xv[k].z*w0.z + xv[k].w*w0.w;
        a1 += xv[k].x*w1.x + xv[k].y*w1.y + xv[k].z*w1.z + xv[k].w*w1.w;
    }
    #pragma unroll
    for (int off = 1; off <= 8; off <<= 1) {
        a0 += __shfl_xor(a0, off);
        a1 += __shfl_xor(a1, off);
    }
    if (j == 0) g[q * 4 + i4] = make_float2(a0, a1);
}

// ---- kernel 2 (fused): blocks [0,NBB) bin edges into their XCD shard;
//      blocks [NBB,GRID) rowdot with 2-deep register prefetch. ----
__global__ __launch_bounds__(256) void k_fused(
    const float* __restrict__ x, float* __restrict__ ws,
    const int* __restrict__ src, const int* __restrict__ dst,
    float2* __restrict__ g) {
    int b = blockIdx.x;
    int tid = threadIdx.x;

    __shared__ vfloat4 Wlds[256];   // [0,128) col0, [128,256) col1 — 4 KB

    if (b < NBB) {
        // --- binning: count -> reserve (sharded) -> place ---
        __shared__ int cnt[NBINS];
        __shared__ int offs[NBINS];
        __shared__ int cur2[NBINS];
        int sg = b & (NSH - 1);
        for (int i = tid; i < NBINS; i += 256) { cnt[i] = 0; cur2[i] = 0; }
        __syncthreads();
        int base = b * CHUNK;
        for (int e = base + tid; e < base + CHUNK; e += 256)
            atomicAdd(&cnt[dst[e] >> BSH], 1);
        __syncthreads();
        int* gcur = reinterpret_cast<int*>(ws + WS_CUR);
        for (int i = tid; i < NBINS; i += 256) {
            int c = cnt[i];
            int pos = c ? atomicAdd(&gcur[i * NSH + sg], c) : 0;
            offs[i] = (i * NSH + sg) * BCAP_S + pos;
        }
        __syncthreads();
        unsigned int* bins = reinterpret_cast<unsigned int*>(ws + WS_BINS);
        for (int e = base + tid; e < base + CHUNK; e += 256) {
            int d = dst[e], s = src[e];
            int bin = d >> BSH;
            int r = atomicAdd(&cur2[bin], 1);
            bins[offs[bin] + r] = (unsigned int)s | ((unsigned int)(d & (BINW - 1)) << 17);
        }
        return;
    }
    // --- stage W into LDS once per block ---
    {
        const vfloat4* Wq = reinterpret_cast<const vfloat4*>(ws + WS_W);
        if (tid < 256) Wlds[tid] = Wq[tid];
        __syncthreads();
    }
    // --- rowdot: 2-deep register double-buffer (issue q+1 loads before
    //     computing q; compiler emits counted vmcnt, wave keeps 8KB in flight)
    int rb = b - NBB;
    int lane = tid & 63;
    int wave = tid >> 6;
    int j = lane & 15, i4 = lane >> 4;
    const vfloat4* W0l = Wlds;
    const vfloat4* W1l = Wlds + 128;

    int wid = rb * 4 + wave;
    int nw  = NRB * 4;                    // 6192
    constexpr int NQ = N_NODES / 4;       // 25000

    vfloat4 xva[8], xvb[8];
    int q = wid;
    if (q >= NQ) return;
    rd_load(xva, x, q, i4, j);
    while (true) {
        int q2 = q + nw;
        if (q2 < NQ) rd_load(xvb, x, q2, i4, j);
        rd_compute(xva, W0l, W1l, g, q, i4, j);
        if (q2 >= NQ) break;
        int q3 = q2 + nw;
        if (q3 < NQ) rd_load(xva, x, q3, i4, j);
        rd_compute(xvb, W0l, W1l, g, q2, i4, j);
        if (q3 >= NQ) break;
        q = q3;
    }
}

// ---- kernel 3: per-bin degree count over 8 shards; deg, dinv, fxp ----
__global__ __launch_bounds__(512) void k_deg(float* __restrict__ ws) {
    int b = blockIdx.x;
    int tid = threadIdx.x;
    const int* gcur = reinterpret_cast<const int*>(ws + WS_CUR);
    const unsigned int* bins = reinterpret_cast<const unsigned int*>(ws + WS_BINS);
    __shared__ int cnt[BINW];
    if (tid < BINW) cnt[tid] = 0;
    __syncthreads();
    #pragma unroll
    for (int sg = 0; sg < NSH; ++sg) {
        int cell = b * NSH + sg;
        int n = min(gcur[cell], BCAP_S);
        const unsigned int* bb = bins + (size_t)cell * BCAP_S;
        for (int i = tid; i < n; i += 512)
            atomicAdd(&cnt[bb[i] >> 17], 1);
    }
    __syncthreads();
    int d = (b << BSH) + tid;
    if (tid < BINW && d < N_NODES) {
        int dg = cnt[tid] + 1;                       // + self-loop
        reinterpret_cast<int*>(ws + WS_DEG)[d] = dg;
        float di = rsqrtf((float)dg);
        ws[WS_DINV + d] = di;
        float2 gv = reinterpret_cast<const float2*>(ws + WS_G)[d];
        unsigned int lo = (unsigned int)__float2int_rn((gv.x * di + FXB) * FXS);
        unsigned int hi = (unsigned int)__float2int_rn((gv.y * di + FXB) * FXS);
        reinterpret_cast<unsigned long long*>(ws + WS_FXP)[d] =
            ((unsigned long long)hi << 32) | (unsigned long long)lo;
    }
}

// ---- kernel 4: per-bin LDS u64 accumulation of fxp[src] over shards ----
__global__ __launch_bounds__(512) void k_pass2(float* __restrict__ ws,
                                               float2* __restrict__ out) {
    int b = blockIdx.x;
    int tid = threadIdx.x;
    const int* gcur = reinterpret_cast<const int*>(ws + WS_CUR);
    const unsigned int* bins = reinterpret_cast<const unsigned int*>(ws + WS_BINS);
    const int* deg = reinterpret_cast<const int*>(ws + WS_DEG);
    const float* dinv = ws + WS_DINV;
    const unsigned long long* fxp = reinterpret_cast<const unsigned long long*>(ws + WS_FXP);
    __shared__ unsigned long long acc[BINW];
    if (tid < BINW) acc[tid] = 0ull;
    __syncthreads();
    #pragma unroll
    for (int sg = 0; sg < NSH; ++sg) {
        int cell = b * NSH + sg;
        int n = min(gcur[cell], BCAP_S);
        const unsigned int* bb = bins + (size_t)cell * BCAP_S;
        int i = tid;
        // 2-way ILP: both gathers issued before the (non-blocking) LDS atomics
        for (; i + 512 < n; i += 1024) {
            unsigned int p0 = bb[i], p1 = bb[i + 512];
            unsigned long long v0 = fxp[p0 & 0x1FFFFu];
            unsigned long long v1 = fxp[p1 & 0x1FFFFu];
            atomicAdd(&acc[p0 >> 17], v0);
            atomicAdd(&acc[p1 >> 17], v1);
        }
        if (i < n) {
            unsigned int p = bb[i];
            atomicAdd(&acc[p >> 17], fxp[p & 0x1FFFFu]);
        }
    }
    __syncthreads();
    int d = (b << BSH) + tid;
    if (tid < BINW && d < N_NODES) {
        unsigned long long a = acc[tid] + fxp[d];    // + self-loop addend
        long long dg = (long long)deg[d];
        long long bias = dg << 25;                   // exact: deg * FXB*FXS
        long long lo = (long long)(a & 0xFFFFFFFFull) - bias;
        long long hi = (long long)(a >> 32) - bias;
        float di = dinv[d];
        out[d] = make_float2(di * ((float)lo * (1.0f / FXS)) + ws[WS_C + 0],
                             di * ((float)hi * (1.0f / FXS)) + ws[WS_C + 1]);
    }
}

extern "C" void kernel_launch(void* const* d_in, const int* in_sizes, int n_in,
                              void* d_out, int out_size, void* d_ws, size_t ws_size,
                              hipStream_t stream) {
    const float* x  = (const float*)d_in[0];
    const float* w1 = (const float*)d_in[1];
    const float* b1 = (const float*)d_in[2];
    const float* w2 = (const float*)d_in[3];
    const float* b2 = (const float*)d_in[4];
    const int*   ei = (const int*)d_in[5];   // [2, E]: src row then dst row
    float* ws = (float*)d_ws;

    float2* g = (float2*)(ws + WS_G);

    k_prep<<<13, 256, 0, stream>>>(w1, w2, b1, b2, ws);
    k_fused<<<GRID, 256, 0, stream>>>(x, ws, ei, ei + N_EDGES, g);
    k_deg<<<NBINS, 512, 0, stream>>>(ws);
    k_pass2<<<NBINS, 512, 0, stream>>>(ws, (float2*)d_out);
}

// Round 16
// 76.901 us; speedup vs baseline: 1.0519x; 1.0519x over previous
//
#include <hip/hip_runtime.h>

constexpr int N_NODES = 100000;
constexpr int N_FEAT  = 512;
constexpr int N_EDGES = 1600000;

// fixed-point packing for LDS u64 accumulation
constexpr float FXS = 1048576.0f;  // 2^20
constexpr float FXB = 32.0f;       // positivity bias; FXB*FXS = 2^25 exact

// binning (R8: narrow; R9: no dynamic sched; R6/R11: no inter-block barriers;
// R13: XCD-sharded bins; R16: tile-contiguous rowdot — 4KB/instruction bursts)
constexpr int BSH    = 8;
constexpr int BINW   = 1 << BSH;                     // 256 nodes/bin
constexpr int NBINS  = (N_NODES + BINW - 1) >> BSH;  // 391
constexpr int NSH    = 8;                            // shards (≈ XCDs)
constexpr int BCAP_S = 768;   // per-(bin,shard): mean 516, +11 sigma
constexpr int NBB    = 500;   // binning blocks
constexpr int CHUNK  = N_EDGES / NBB;                // 3200 (exact)
constexpr int GRID   = 2048;
constexpr int NRB    = GRID - NBB;                   // 1548 rowdot blocks
constexpr int NCUR   = NBINS * NSH;                  // 3128 cursors

// rowdot tiling: 16 rows = 32KB per tile; contiguous slab per block
constexpr int TROWS  = 16;
constexpr int NTILE  = N_NODES / TROWS;              // 6250 (exact)
constexpr int TSPLIT = NTILE - NRB * 4;              // 58 blocks get 5 tiles
static_assert(TSPLIT >= 0 && TSPLIT < NRB, "tile split");
constexpr int SCR_STRIDE = 136;                      // 128 + 8 pad (bank rotate)

typedef float vfloat4 __attribute__((ext_vector_type(4)));

// ws float offsets
constexpr int WS_W    = 0;                    // [0,1024) two cols of w1@w2
constexpr int WS_C    = 1024;                 // c (pad to 1056)
constexpr int WS_CUR  = 1056;                 // NCUR cursors (pad 3200)
constexpr int WS_DEG  = WS_CUR + 3200;        // deg[N] int
constexpr int WS_DINV = WS_DEG + N_NODES;     // dinv[N]
constexpr int WS_G    = WS_DINV + N_NODES;    // g[N,2] (byte%8==0)
constexpr int WS_FXP  = WS_G + 2 * N_NODES;   // u64[N] packed addends
constexpr int WS_BINS = WS_FXP + 2 * N_NODES; // u32[NCUR*BCAP_S] ~9.6MB

static_assert((WS_G * 4) % 8 == 0, "g alignment");
static_assert((WS_FXP * 4) % 8 == 0, "fxp alignment");

// ---- kernel 1: W = w1@w2, c = b1@w2+b2, zero cursors ----
__global__ void k_prep(const float* __restrict__ w1, const float* __restrict__ w2,
                       const float* __restrict__ b1, const float* __restrict__ b2,
                       float* __restrict__ ws) {
    int i = blockIdx.x * blockDim.x + threadIdx.x;
    if (i < NCUR) reinterpret_cast<int*>(ws + WS_CUR)[i] = 0;
    if (i < N_FEAT) {
        float a0 = 0.f, a1 = 0.f;
        for (int m = 0; m < 128; ++m) {
            float w = w1[i * 128 + m];
            a0 += w * w2[m * 2 + 0];
            a1 += w * w2[m * 2 + 1];
        }
        ws[WS_W + i] = a0;
        ws[WS_W + 512 + i] = a1;
        if (i < 2) {
            float s = b2[i];
            for (int m = 0; m < 128; ++m) s += b1[m] * w2[m * 2 + i];
            ws[WS_C + i] = s;
        }
    }
}

// ---- kernel 2 (fused): blocks [0,NBB) bin edges into their XCD shard;
//      blocks [NBB,GRID) rowdot over contiguous 16-row tiles:
//      8 × 4KB fully-contiguous loads, W fixed per thread (registers),
//      LDS transpose + 16-lane shuffle reduce. ----
__global__ __launch_bounds__(256) void k_fused(
    const float* __restrict__ x, float* __restrict__ ws,
    const int* __restrict__ src, const int* __restrict__ dst,
    float2* __restrict__ g) {
    int b = blockIdx.x;
    int tid = threadIdx.x;

    __shared__ __align__(16) char smem[2 * TROWS * SCR_STRIDE * 4];  // 17408 B

    if (b < NBB) {
        // --- binning: count -> reserve (sharded) -> place ---
        int* cnt  = reinterpret_cast<int*>(smem);
        int* offs = cnt + NBINS;
        int* cur2 = offs + NBINS;
        int sg = b & (NSH - 1);
        for (int i = tid; i < NBINS; i += 256) { cnt[i] = 0; cur2[i] = 0; }
        __syncthreads();
        int base = b * CHUNK;
        for (int e = base + tid; e < base + CHUNK; e += 256)
            atomicAdd(&cnt[dst[e] >> BSH], 1);
        __syncthreads();
        int* gcur = reinterpret_cast<int*>(ws + WS_CUR);
        for (int i = tid; i < NBINS; i += 256) {
            int c = cnt[i];
            int pos = c ? atomicAdd(&gcur[i * NSH + sg], c) : 0;
            offs[i] = (i * NSH + sg) * BCAP_S + pos;
        }
        __syncthreads();
        unsigned int* bins = reinterpret_cast<unsigned int*>(ws + WS_BINS);
        for (int e = base + tid; e < base + CHUNK; e += 256) {
            int d = dst[e], s = src[e];
            int bin = d >> BSH;
            int r = atomicAdd(&cur2[bin], 1);
            bins[offs[bin] + r] = (unsigned int)s | ((unsigned int)(d & (BINW - 1)) << 17);
        }
        return;
    }

    // --- rowdot ---
    float (*scrA)[SCR_STRIDE] = reinterpret_cast<float (*)[SCR_STRIDE]>(smem);
    float (*scrB)[SCR_STRIDE] =
        reinterpret_cast<float (*)[SCR_STRIDE]>(smem + TROWS * SCR_STRIDE * 4);

    int rb = b - NBB;                      // 0..NRB-1
    int t0, tcnt;
    if (rb < TSPLIT) { t0 = rb * 5;                     tcnt = 5; }
    else             { t0 = TSPLIT * 5 + (rb - TSPLIT) * 4; tcnt = 4; }

    int c = tid & 127;                     // this thread's fixed W column-chunk
    int row_lo = tid >> 7;                 // 0 or 1
    const vfloat4* Wq = reinterpret_cast<const vfloat4*>(ws + WS_W);
    vfloat4 w0c = Wq[c];
    vfloat4 w1c = Wq[128 + c];

    int lane16 = tid & 15;
    int rrow   = tid >> 4;                 // 0..15 (reduction row)

    for (int tt = t0; tt < t0 + tcnt; ++tt) {
        int r0 = tt * TROWS;
        const vfloat4* xq = reinterpret_cast<const vfloat4*>(x) + (size_t)r0 * 128;
        vfloat4 xv[8];
        #pragma unroll
        for (int i = 0; i < 8; ++i)
            xv[i] = xq[i * 256 + tid];     // 4KB fully-contiguous per instruction
        #pragma unroll
        for (int i = 0; i < 8; ++i) {
            float pa = xv[i].x*w0c.x + xv[i].y*w0c.y + xv[i].z*w0c.z + xv[i].w*w0c.w;
            float pb = xv[i].x*w1c.x + xv[i].y*w1c.y + xv[i].z*w1c.z + xv[i].w*w1c.w;
            scrA[2 * i + row_lo][c] = pa;
            scrB[2 * i + row_lo][c] = pb;
        }
        __syncthreads();
        // reduce: row rrow's 128 partials -> 16 lanes x 8 each -> shfl tree
        const float4* rA = reinterpret_cast<const float4*>(&scrA[rrow][0]);
        const float4* rB = reinterpret_cast<const float4*>(&scrB[rrow][0]);
        float4 aq0 = rA[lane16 * 2], aq1 = rA[lane16 * 2 + 1];
        float4 bq0 = rB[lane16 * 2], bq1 = rB[lane16 * 2 + 1];
        float sa = aq0.x + aq0.y + aq0.z + aq0.w + aq1.x + aq1.y + aq1.z + aq1.w;
        float sb = bq0.x + bq0.y + bq0.z + bq0.w + bq1.x + bq1.y + bq1.z + bq1.w;
        #pragma unroll
        for (int off = 1; off <= 8; off <<= 1) {
            sa += __shfl_xor(sa, off);
            sb += __shfl_xor(sb, off);
        }
        if (lane16 == 0) g[r0 + rrow] = make_float2(sa, sb);
        __syncthreads();
    }
}

// ---- kernel 3: per-bin degree count over 8 shards; deg, dinv, fxp ----
__global__ __launch_bounds__(512) void k_deg(float* __restrict__ ws) {
    int b = blockIdx.x;
    int tid = threadIdx.x;
    const int* gcur = reinterpret_cast<const int*>(ws + WS_CUR);
    const unsigned int* bins = reinterpret_cast<const unsigned int*>(ws + WS_BINS);
    __shared__ int cnt[BINW];
    if (tid < BINW) cnt[tid] = 0;
    __syncthreads();
    #pragma unroll
    for (int sg = 0; sg < NSH; ++sg) {
        int cell = b * NSH + sg;
        int n = min(gcur[cell], BCAP_S);
        const unsigned int* bb = bins + (size_t)cell * BCAP_S;
        for (int i = tid; i < n; i += 512)
            atomicAdd(&cnt[bb[i] >> 17], 1);
    }
    __syncthreads();
    int d = (b << BSH) + tid;
    if (tid < BINW && d < N_NODES) {
        int dg = cnt[tid] + 1;                       // + self-loop
        reinterpret_cast<int*>(ws + WS_DEG)[d] = dg;
        float di = rsqrtf((float)dg);
        ws[WS_DINV + d] = di;
        float2 gv = reinterpret_cast<const float2*>(ws + WS_G)[d];
        unsigned int lo = (unsigned int)__float2int_rn((gv.x * di + FXB) * FXS);
        unsigned int hi = (unsigned int)__float2int_rn((gv.y * di + FXB) * FXS);
        reinterpret_cast<unsigned long long*>(ws + WS_FXP)[d] =
            ((unsigned long long)hi << 32) | (unsigned long long)lo;
    }
}

// ---- kernel 4: per-bin LDS u64 accumulation of fxp[src] over shards ----
__global__ __launch_bounds__(512) void k_pass2(float* __restrict__ ws,
                                               float2* __restrict__ out) {
    int b = blockIdx.x;
    int tid = threadIdx.x;
    const int* gcur = reinterpret_cast<const int*>(ws + WS_CUR);
    const unsigned int* bins = reinterpret_cast<const unsigned int*>(ws + WS_BINS);
    const int* deg = reinterpret_cast<const int*>(ws + WS_DEG);
    const float* dinv = ws + WS_DINV;
    const unsigned long long* fxp = reinterpret_cast<const unsigned long long*>(ws + WS_FXP);
    __shared__ unsigned long long acc[BINW];
    if (tid < BINW) acc[tid] = 0ull;
    __syncthreads();
    #pragma unroll
    for (int sg = 0; sg < NSH; ++sg) {
        int cell = b * NSH + sg;
        int n = min(gcur[cell], BCAP_S);
        const unsigned int* bb = bins + (size_t)cell * BCAP_S;
        int i = tid;
        for (; i + 512 < n; i += 1024) {
            unsigned int p0 = bb[i], p1 = bb[i + 512];
            unsigned long long v0 = fxp[p0 & 0x1FFFFu];
            unsigned long long v1 = fxp[p1 & 0x1FFFFu];
            atomicAdd(&acc[p0 >> 17], v0);
            atomicAdd(&acc[p1 >> 17], v1);
        }
        if (i < n) {
            unsigned int p = bb[i];
            atomicAdd(&acc[p >> 17], fxp[p & 0x1FFFFu]);
        }
    }
    __syncthreads();
    int d = (b << BSH) + tid;
    if (tid < BINW && d < N_NODES) {
        unsigned long long a = acc[tid] + fxp[d];    // + self-loop addend
        long long dg = (long long)deg[d];
        long long bias = dg << 25;                   // exact: deg * FXB*FXS
        long long lo = (long long)(a & 0xFFFFFFFFull) - bias;
        long long hi = (long long)(a >> 32) - bias;
        float di = dinv[d];
        out[d] = make_float2(di * ((float)lo * (1.0f / FXS)) + ws[WS_C + 0],
                             di * ((float)hi * (1.0f / FXS)) + ws[WS_C + 1]);
    }
}

extern "C" void kernel_launch(void* const* d_in, const int* in_sizes, int n_in,
                              void* d_out, int out_size, void* d_ws, size_t ws_size,
                              hipStream_t stream) {
    const float* x  = (const float*)d_in[0];
    const float* w1 = (const float*)d_in[1];
    const float* b1 = (const float*)d_in[2];
    const float* w2 = (const float*)d_in[3];
    const float* b2 = (const float*)d_in[4];
    const int*   ei = (const int*)d_in[5];   // [2, E]: src row then dst row
    float* ws = (float*)d_ws;

    float2* g = (float2*)(ws + WS_G);

    k_prep<<<13, 256, 0, stream>>>(w1, w2, b1, b2, ws);
    k_fused<<<GRID, 256, 0, stream>>>(x, ws, ei, ei + N_EDGES, g);
    k_deg<<<NBINS, 512, 0, stream>>>(ws);
    k_pass2<<<NBINS, 512, 0, stream>>>(ws, (float2*)d_out);
}